// Round 1
// baseline (1386.214 us; speedup 1.0000x reference)
//
#include <hip/hip_runtime.h>
#include <hip/hip_bf16.h>

#define NRES 320
#define CZ 128
#define NH 4
#define CH 32
#define DM 128
#define NPOS (NRES*NRES)
#define LN_EPS 1e-5f
#define QSCALE 0.17677669529663687f

using bf16 = __hip_bfloat16;

__device__ __forceinline__ float bflo(uint32_t u){ return __uint_as_float(u << 16); }
__device__ __forceinline__ float bfhi(uint32_t u){ return __uint_as_float(u & 0xffff0000u); }
__device__ __forceinline__ bf16 tob(float f){ return __float2bfloat16(f); }

// ---------------- Kernel 1: LayerNorm + QKVG projection ----------------
// grid (NPOS/64, 4), block 256.  nb=0:q 1:k 2:v 3:g
__global__ __launch_bounds__(256)
void k_lnproj(const float* __restrict__ z, const float* __restrict__ ln_w,
              const float* __restrict__ ln_b, const float* __restrict__ wq,
              const float* __restrict__ wk, const float* __restrict__ wv,
              const float* __restrict__ wg, bf16* __restrict__ qws,
              bf16* __restrict__ kws, bf16* __restrict__ vws,
              bf16* __restrict__ gws)
{
    __shared__ float As[64][CZ];    // z tile -> zn in place
    __shared__ float Bs[CZ][129];   // Bs[d][e] = w[e][d]
    const int tid = threadIdx.x;
    const int p0 = blockIdx.x * 64;
    const int nb = blockIdx.y;

    // A tile: 64*128 contiguous floats
    {
        const float4* src = (const float4*)(z + (size_t)p0 * CZ);
        float4* dst = (float4*)(&As[0][0]);
        #pragma unroll
        for (int it = 0; it < 8; ++it) dst[tid + it*256] = src[tid + it*256];
    }
    // B tile transposed into LDS
    {
        const float* w = (nb==0)?wq:(nb==1)?wk:(nb==2)?wv:wg;
        #pragma unroll 8
        for (int it = 0; it < 64; ++it) {
            const int flat = tid + it*256;          // [e][d] row-major
            Bs[flat & 127][flat >> 7] = w[flat];
        }
    }
    __syncthreads();
    // LayerNorm: 4 threads per row
    {
        const int r = tid >> 2, part = (tid & 3) * 32;
        float s = 0.f, s2 = 0.f;
        #pragma unroll
        for (int c = 0; c < 32; ++c) { const float v = As[r][part+c]; s += v; s2 += v*v; }
        s  += __shfl_xor(s, 1);  s  += __shfl_xor(s, 2);
        s2 += __shfl_xor(s2, 1); s2 += __shfl_xor(s2, 2);
        const float mu = s * 0.0078125f;
        const float rs = rsqrtf(s2 * 0.0078125f - mu*mu + LN_EPS);
        #pragma unroll
        for (int c = 0; c < 32; ++c) {
            const int cc = part + c;
            As[r][cc] = (As[r][cc] - mu) * rs * ln_w[cc] + ln_b[cc];
        }
    }
    __syncthreads();
    // 4x8 micro-tile GEMM
    const int tx = tid & 15, ty = tid >> 4;
    const int m0 = ty * 4, n0 = tx * 8;
    float acc[4][8];
    #pragma unroll
    for (int a = 0; a < 4; ++a)
        #pragma unroll
        for (int b = 0; b < 8; ++b) acc[a][b] = 0.f;
    for (int k = 0; k < CZ; ++k) {
        float av[4], bv[8];
        #pragma unroll
        for (int a = 0; a < 4; ++a) av[a] = As[m0+a][k];
        #pragma unroll
        for (int b = 0; b < 8; ++b) bv[b] = Bs[k][n0+b];
        #pragma unroll
        for (int a = 0; a < 4; ++a)
            #pragma unroll
            for (int b = 0; b < 8; ++b) acc[a][b] = fmaf(av[a], bv[b], acc[a][b]);
    }
    // epilogue
    #pragma unroll
    for (int a = 0; a < 4; ++a) {
        const int p = p0 + m0 + a;
        const int ii = p / NRES, jj = p % NRES;
        #pragma unroll
        for (int b = 0; b < 8; ++b) {
            const int e = n0 + b;
            const float v = acc[a][b];
            const size_t hidx = (size_t)(((ii*NH + (e>>5))*NRES + jj)*CH) + (e & 31);
            if (nb == 0)      qws[hidx] = tob(v * QSCALE);
            else if (nb == 1) kws[hidx] = tob(v);
            else if (nb == 2) vws[hidx] = tob(v);
            else              gws[(size_t)p*DM + e] = tob(1.f / (1.f + __expf(-v)));
        }
    }
}

// ---------------- Kernel 2: attention per (i, h) ----------------
// grid (NRES, NH), block 320 (one query per thread)
__global__ __launch_bounds__(320)
void k_attn(const bf16* __restrict__ qws, const bf16* __restrict__ kws,
            const bf16* __restrict__ vws, const bf16* __restrict__ gws,
            const float* __restrict__ mask_bias, const float* __restrict__ edge_bias,
            bf16* __restrict__ ows)
{
    __shared__ float Ks[NRES][CH];   // 40 KB
    __shared__ float Vs[NRES][CH];   // 40 KB
    __shared__ float Es[NRES][33];   // 42 KB, edge-bias chunk (padded)
    const int i = blockIdx.x, h = blockIdx.y, tid = threadIdx.x;
    const size_t slab = (size_t)(i*NH + h) * NRES * CH;

    {
        const uint32_t* kp = (const uint32_t*)(kws + slab);
        const uint32_t* vp = (const uint32_t*)(vws + slab);
        float* Kf = &Ks[0][0];
        float* Vf = &Vs[0][0];
        #pragma unroll
        for (int it = 0; it < 16; ++it) {
            const int idx = tid + it*320;
            uint32_t u = kp[idx];
            Kf[2*idx] = bflo(u); Kf[2*idx+1] = bfhi(u);
            u = vp[idx];
            Vf[2*idx] = bflo(u); Vf[2*idx+1] = bfhi(u);
        }
    }
    float qr[32];
    {
        const uint32_t* qp = (const uint32_t*)(qws + slab + (size_t)tid*CH);
        #pragma unroll
        for (int c = 0; c < 16; ++c) {
            const uint32_t u = qp[c];
            qr[2*c] = bflo(u); qr[2*c+1] = bfhi(u);
        }
    }
    float m = -1e30f, l = 0.f;
    float o[CH];
    #pragma unroll
    for (int c = 0; c < CH; ++c) o[c] = 0.f;

    const float* mb = mask_bias + (size_t)i * NRES;
    const float* eb = edge_bias + (size_t)h * NRES * NRES;   // [q][k]

    for (int k0 = 0; k0 < NRES; k0 += 32) {
        __syncthreads();
        #pragma unroll
        for (int it = 0; it < 32; ++it) {
            const int f = tid + it*320;                       // 10240 elems
            Es[f >> 5][f & 31] = eb[(size_t)(f >> 5)*NRES + k0 + (f & 31)];
        }
        __syncthreads();
        for (int kk = 0; kk < 32; ++kk) {
            const int k = k0 + kk;
            float s0 = 0.f, s1 = 0.f, s2 = 0.f, s3 = 0.f;
            #pragma unroll
            for (int c = 0; c < 8; ++c) {
                s0 = fmaf(qr[4*c+0], Ks[k][4*c+0], s0);
                s1 = fmaf(qr[4*c+1], Ks[k][4*c+1], s1);
                s2 = fmaf(qr[4*c+2], Ks[k][4*c+2], s2);
                s3 = fmaf(qr[4*c+3], Ks[k][4*c+3], s3);
            }
            const float s = mb[k] + Es[tid][kk] + ((s0+s1)+(s2+s3));
            const float mn = fmaxf(m, s);
            if (mn > m) {
                const float sc = __expf(m - mn);
                l *= sc;
                #pragma unroll
                for (int c = 0; c < CH; ++c) o[c] *= sc;
                m = mn;
            }
            const float p = __expf(s - m);
            l += p;
            #pragma unroll
            for (int c = 0; c < CH; ++c) o[c] = fmaf(p, Vs[k][c], o[c]);
        }
    }
    const float linv = 1.f / l;
    const size_t ob = ((size_t)(i*NRES) + tid) * DM + h*CH;
    #pragma unroll
    for (int c = 0; c < CH; ++c) {
        const float gv = __bfloat162float(gws[ob + c]);
        ows[ob + c] = tob(o[c] * linv * gv);
    }
}

// ---------------- Kernel 3: output projection ----------------
// grid NPOS/64, block 256
__global__ __launch_bounds__(256)
void k_outproj(const bf16* __restrict__ ows, const float* __restrict__ wo,
               float* __restrict__ out)
{
    __shared__ float As[64][CZ];
    __shared__ float Bs[CZ][129];   // Bs[e][d] = wo[d][e]
    const int tid = threadIdx.x;
    const int p0 = blockIdx.x * 64;
    {
        const uint32_t* src = (const uint32_t*)(ows + (size_t)p0 * DM);
        float* Af = &As[0][0];
        #pragma unroll
        for (int it = 0; it < 16; ++it) {
            const int idx = tid + it*256;
            const uint32_t u = src[idx];
            Af[2*idx] = bflo(u); Af[2*idx+1] = bfhi(u);
        }
    }
    {
        #pragma unroll 8
        for (int it = 0; it < 64; ++it) {
            const int flat = tid + it*256;            // wo [d][e] row-major
            Bs[flat & 127][flat >> 7] = wo[flat];
        }
    }
    __syncthreads();
    const int tx = tid & 15, ty = tid >> 4;
    const int m0 = ty * 4, n0 = tx * 8;
    float acc[4][8];
    #pragma unroll
    for (int a = 0; a < 4; ++a)
        #pragma unroll
        for (int b = 0; b < 8; ++b) acc[a][b] = 0.f;
    for (int k = 0; k < CZ; ++k) {
        float av[4], bv[8];
        #pragma unroll
        for (int a = 0; a < 4; ++a) av[a] = As[m0+a][k];
        #pragma unroll
        for (int b = 0; b < 8; ++b) bv[b] = Bs[k][n0+b];
        #pragma unroll
        for (int a = 0; a < 4; ++a)
            #pragma unroll
            for (int b = 0; b < 8; ++b) acc[a][b] = fmaf(av[a], bv[b], acc[a][b]);
    }
    #pragma unroll
    for (int a = 0; a < 4; ++a) {
        float4* dst = (float4*)(out + (size_t)(p0 + m0 + a)*DM + n0);
        dst[0] = make_float4(acc[a][0], acc[a][1], acc[a][2], acc[a][3]);
        dst[1] = make_float4(acc[a][4], acc[a][5], acc[a][6], acc[a][7]);
    }
}

extern "C" void kernel_launch(void* const* d_in, const int* in_sizes, int n_in,
                              void* d_out, int out_size, void* d_ws, size_t ws_size,
                              hipStream_t stream)
{
    const float* z   = (const float*)d_in[0];
    const float* mb  = (const float*)d_in[1];
    const float* eb  = (const float*)d_in[2];
    const float* wq  = (const float*)d_in[3];
    const float* wk  = (const float*)d_in[4];
    const float* wv  = (const float*)d_in[5];
    const float* wg  = (const float*)d_in[6];
    const float* wo  = (const float*)d_in[7];
    const float* lnw = (const float*)d_in[8];
    const float* lnb = (const float*)d_in[9];
    float* out = (float*)d_out;

    const size_t SEG = (size_t)NPOS * DM;   // 13,107,200 elements
    bf16* qws = (bf16*)d_ws;
    bf16* kws = qws + SEG;
    bf16* vws = kws + SEG;
    bf16* gws = vws + SEG;
    bf16* ows = gws + SEG;   // total 131,072,000 bytes of ws

    k_lnproj<<<dim3(NPOS/64, 4), 256, 0, stream>>>(z, lnw, lnb, wq, wk, wv, wg,
                                                   qws, kws, vws, gws);
    k_attn<<<dim3(NRES, NH), 320, 0, stream>>>(qws, kws, vws, gws, mb, eb, ows);
    k_outproj<<<NPOS/64, 256, 0, stream>>>(ows, wo, out);
}

// Round 4
// 732.595 us; speedup vs baseline: 1.8922x; 1.8922x over previous
//
#include <hip/hip_runtime.h>
#include <hip/hip_bf16.h>

#define NRES 320
#define CZ 128
#define NH 4
#define CH 32
#define DM 128
#define NPOS (NRES*NRES)
#define LN_EPS 1e-5f
#define QSCALE 0.17677669529663687f

using bf16 = __hip_bfloat16;
typedef __attribute__((ext_vector_type(8))) short short8;
typedef __attribute__((ext_vector_type(4))) float floatx4;

__device__ __forceinline__ float bflo(uint32_t u){ return __uint_as_float(u << 16); }
__device__ __forceinline__ float bfhi(uint32_t u){ return __uint_as_float(u & 0xffff0000u); }
__device__ __forceinline__ bf16 tob(float f){ return __float2bfloat16(f); }
__device__ __forceinline__ unsigned short f2bu(float f){
    uint32_t u = __float_as_uint(f);
    uint32_t r = (u + 0x7fffu + ((u >> 16) & 1u)) >> 16;   // RNE
    return (unsigned short)r;
}
__device__ __forceinline__ float bu2f(unsigned short b){
    return __uint_as_float((uint32_t)b << 16);
}
__device__ __forceinline__ uint4 pk8(const unsigned short* u){
    uint4 r;
    r.x = (uint32_t)u[0] | ((uint32_t)u[1] << 16);
    r.y = (uint32_t)u[2] | ((uint32_t)u[3] << 16);
    r.z = (uint32_t)u[4] | ((uint32_t)u[5] << 16);
    r.w = (uint32_t)u[6] | ((uint32_t)u[7] << 16);
    return r;
}

// ---------- pack QKVG weights (hi+lo split) into MFMA B-fragment order ----------
// idx -> [wn(8)][ks(4)][nr(4)][lane(64)][j(8)]; B[k][n] = W(n>>7)[n&127][k]
__global__ __launch_bounds__(256)
void k_packw(const float* __restrict__ wq, const float* __restrict__ wk,
             const float* __restrict__ wv, const float* __restrict__ wg,
             bf16* __restrict__ Bpkh, bf16* __restrict__ Bpkl)
{
    const int idx = blockIdx.x * 256 + threadIdx.x;          // 0..65535
    const int j = idx & 7, lane = (idx >> 3) & 63;
    const int nr = (idx >> 9) & 3, ks = (idx >> 11) & 3, wn = idx >> 13;
    const int n = wn*64 + nr*16 + (lane & 15);
    const int k = ks*32 + ((lane >> 4) << 3) + j;
    const float* w = (n >> 7) == 0 ? wq : (n >> 7) == 1 ? wk : (n >> 7) == 2 ? wv : wg;
    const float wv_ = w[(n & 127)*CZ + k];
    const bf16 hb = tob(wv_);
    Bpkh[idx] = hb;
    Bpkl[idx] = tob(wv_ - __bfloat162float(hb));
}

// ---------- pack wo (hi+lo): [wn(2)][ks(4)][nr(4)][lane(64)][j(8)] ----------
__global__ __launch_bounds__(256)
void k_packwo(const float* __restrict__ wo, bf16* __restrict__ B2h,
              bf16* __restrict__ B2l)
{
    const int idx = blockIdx.x * 256 + threadIdx.x;          // 0..16383
    const int j = idx & 7, lane = (idx >> 3) & 63;
    const int nr = (idx >> 9) & 3, ks = (idx >> 11) & 3, wn = idx >> 13;
    const int n = wn*64 + nr*16 + (lane & 15);
    const int k = ks*32 + ((lane >> 4) << 3) + j;
    const float wv_ = wo[n*DM + k];
    const bf16 hb = tob(wv_);
    B2h[idx] = hb;
    B2l[idx] = tob(wv_ - __bfloat162float(hb));
}

// ---------- Kernel 1: LN + QKVG projection, split-bf16 MFMA ----------
// grid NPOS/64, block 512 (8 waves; wave wid owns output cols [wid*64, wid*64+64))
__global__ __launch_bounds__(512)
void k_lnproj(const float* __restrict__ z, const float* __restrict__ ln_w,
              const float* __restrict__ ln_b, const bf16* __restrict__ Bpkh,
              const bf16* __restrict__ Bpkl,
              bf16* __restrict__ qws, bf16* __restrict__ kws,
              bf16* __restrict__ vws, bf16* __restrict__ gows)
{
    __shared__ __align__(16) char Ash[64 * 256];   // zn_hi bf16 [64][128], swizzled
    __shared__ __align__(16) char Asl[64 * 256];   // zn_lo
    const int tid = threadIdx.x;
    const int p0 = blockIdx.x * 64;
    const int lane = tid & 63, wid = tid >> 6;

    // B_hi fragments resident (64 VGPRs); B_lo loaded in-loop (L2-hot)
    short8 bh[4][4];
    {
        const uint4* bp = (const uint4*)Bpkh;
        #pragma unroll
        for (int ks = 0; ks < 4; ++ks)
            #pragma unroll
            for (int nr = 0; nr < 4; ++nr) {
                uint4 t = bp[(((wid*4 + ks)*4) + nr)*64 + lane];
                bh[ks][nr] = *(short8*)&t;
            }
    }

    // LayerNorm: 8 threads per row, 16 cols each; emit hi+lo bf16
    {
        const int r = tid >> 3, c0 = (tid & 7) * 16;
        const float* zp = z + (size_t)(p0 + r)*CZ + c0;
        float v[16];
        {
            float4 t0 = *(const float4*)(zp + 0);
            float4 t1 = *(const float4*)(zp + 4);
            float4 t2 = *(const float4*)(zp + 8);
            float4 t3 = *(const float4*)(zp + 12);
            v[0]=t0.x; v[1]=t0.y; v[2]=t0.z; v[3]=t0.w;
            v[4]=t1.x; v[5]=t1.y; v[6]=t1.z; v[7]=t1.w;
            v[8]=t2.x; v[9]=t2.y; v[10]=t2.z; v[11]=t2.w;
            v[12]=t3.x; v[13]=t3.y; v[14]=t3.z; v[15]=t3.w;
        }
        float s = 0.f, s2 = 0.f;
        #pragma unroll
        for (int c = 0; c < 16; ++c) { s += v[c]; s2 = fmaf(v[c], v[c], s2); }
        s  += __shfl_xor(s, 1);  s  += __shfl_xor(s, 2);  s  += __shfl_xor(s, 4);
        s2 += __shfl_xor(s2, 1); s2 += __shfl_xor(s2, 2); s2 += __shfl_xor(s2, 4);
        const float mu = s * 0.0078125f;
        const float rs = rsqrtf(s2 * 0.0078125f - mu*mu + LN_EPS);
        unsigned short uh[16], ul[16];
        #pragma unroll
        for (int c = 0; c < 16; ++c) {
            const float vn = (v[c] - mu) * rs * ln_w[c0 + c] + ln_b[c0 + c];
            const unsigned short h = f2bu(vn);
            uh[c] = h;
            ul[c] = f2bu(vn - bu2f(h));
        }
        const int base = r*256 + c0*2;
        const int swz = (r & 7) << 4;
        *(uint4*)(Ash + ((base     ) ^ swz)) = pk8(&uh[0]);
        *(uint4*)(Ash + ((base + 16) ^ swz)) = pk8(&uh[8]);
        *(uint4*)(Asl + ((base     ) ^ swz)) = pk8(&ul[0]);
        *(uint4*)(Asl + ((base + 16) ^ swz)) = pk8(&ul[8]);
    }
    __syncthreads();

    floatx4 acc[4][4];
    #pragma unroll
    for (int m = 0; m < 4; ++m)
        #pragma unroll
        for (int n = 0; n < 4; ++n)
            acc[m][n] = (floatx4){0.f, 0.f, 0.f, 0.f};

    const uint4* bpl = (const uint4*)Bpkl;
    #pragma unroll
    for (int ks = 0; ks < 4; ++ks) {
        short8 ah[4], al[4];
        #pragma unroll
        for (int m = 0; m < 4; ++m) {
            const int row = m*16 + (lane & 15);
            const int kb = ks*64 + ((lane >> 4) << 4);
            const int off = (row*256 + kb) ^ ((row & 7) << 4);
            ah[m] = *(const short8*)(Ash + off);
            al[m] = *(const short8*)(Asl + off);
        }
        #pragma unroll
        for (int nr = 0; nr < 4; ++nr) {
            uint4 tl = bpl[(((wid*4 + ks)*4) + nr)*64 + lane];
            const short8 bl = *(short8*)&tl;
            #pragma unroll
            for (int m = 0; m < 4; ++m)
                acc[m][nr] = __builtin_amdgcn_mfma_f32_16x16x32_bf16(ah[m], bh[ks][nr], acc[m][nr], 0, 0, 0);
            #pragma unroll
            for (int m = 0; m < 4; ++m)
                acc[m][nr] = __builtin_amdgcn_mfma_f32_16x16x32_bf16(al[m], bh[ks][nr], acc[m][nr], 0, 0, 0);
            #pragma unroll
            for (int m = 0; m < 4; ++m)
                acc[m][nr] = __builtin_amdgcn_mfma_f32_16x16x32_bf16(ah[m], bl, acc[m][nr], 0, 0, 0);
        }
    }

    // epilogue: e = wid*64 + n*16 + (lane&15); wave-uniform q/k/v/g branch
    const int i = p0 / NRES;          // blocks never straddle i (320 % 64 == 0)
    const int j0 = p0 % NRES;
    #pragma unroll
    for (int n = 0; n < 4; ++n) {
        const int e = wid*64 + n*16 + (lane & 15);
        const int h = (e >> 5) & 3, c = e & 31;
        #pragma unroll
        for (int m = 0; m < 4; ++m) {
            const int rl0 = m*16 + ((lane >> 4) << 2);
            #pragma unroll
            for (int r = 0; r < 4; ++r) {
                const float val = acc[m][n][r];
                const int jj = j0 + rl0 + r;
                const size_t hidx = ((size_t)((i*NH + h)*NRES) + jj)*CH + c;
                if (wid < 2)       qws[hidx] = tob(val * QSCALE);
                else if (wid < 4)  kws[hidx] = tob(val);
                else if (wid < 6)  vws[hidx] = tob(val);
                else gows[(size_t)(p0 + rl0 + r)*DM + (e & 127)] =
                         tob(1.f / (1.f + __expf(-val)));
            }
        }
    }
}

// ---------------- Kernel 2: attention per (i, h); g -> o in place ----------------
__global__ __launch_bounds__(320)
void k_attn(const bf16* __restrict__ qws, const bf16* __restrict__ kws,
            const bf16* __restrict__ vws, bf16* __restrict__ gows,
            const float* __restrict__ mask_bias, const float* __restrict__ edge_bias)
{
    __shared__ float Ks[NRES][CH];
    __shared__ float Vs[NRES][CH];
    __shared__ float Es[NRES][33];
    const int i = blockIdx.x, h = blockIdx.y, tid = threadIdx.x;
    const size_t slab = (size_t)(i*NH + h) * NRES * CH;

    {
        const uint32_t* kp = (const uint32_t*)(kws + slab);
        const uint32_t* vp = (const uint32_t*)(vws + slab);
        float* Kf = &Ks[0][0];
        float* Vf = &Vs[0][0];
        #pragma unroll
        for (int it = 0; it < 16; ++it) {
            const int idx = tid + it*320;
            uint32_t u = kp[idx];
            Kf[2*idx] = bflo(u); Kf[2*idx+1] = bfhi(u);
            u = vp[idx];
            Vf[2*idx] = bflo(u); Vf[2*idx+1] = bfhi(u);
        }
    }
    float qr[32];
    {
        const uint32_t* qp = (const uint32_t*)(qws + slab + (size_t)tid*CH);
        #pragma unroll
        for (int c = 0; c < 16; ++c) {
            const uint32_t u = qp[c];
            qr[2*c] = bflo(u); qr[2*c+1] = bfhi(u);
        }
    }
    float m = -1e30f, l = 0.f;
    float o[CH];
    #pragma unroll
    for (int c = 0; c < CH; ++c) o[c] = 0.f;

    const float* mb = mask_bias + (size_t)i * NRES;
    const float* eb = edge_bias + (size_t)h * NRES * NRES;

    for (int k0 = 0; k0 < NRES; k0 += 32) {
        __syncthreads();
        #pragma unroll
        for (int it = 0; it < 32; ++it) {
            const int f = tid + it*320;
            Es[f >> 5][f & 31] = eb[(size_t)(f >> 5)*NRES + k0 + (f & 31)];
        }
        __syncthreads();
        for (int kk = 0; kk < 32; ++kk) {
            const int k = k0 + kk;
            float s0 = 0.f, s1 = 0.f, s2 = 0.f, s3 = 0.f;
            #pragma unroll
            for (int c = 0; c < 8; ++c) {
                s0 = fmaf(qr[4*c+0], Ks[k][4*c+0], s0);
                s1 = fmaf(qr[4*c+1], Ks[k][4*c+1], s1);
                s2 = fmaf(qr[4*c+2], Ks[k][4*c+2], s2);
                s3 = fmaf(qr[4*c+3], Ks[k][4*c+3], s3);
            }
            const float s = mb[k] + Es[tid][kk] + ((s0+s1)+(s2+s3));
            const float mn = fmaxf(m, s);
            if (mn > m) {
                const float sc = __expf(m - mn);
                l *= sc;
                #pragma unroll
                for (int c = 0; c < CH; ++c) o[c] *= sc;
                m = mn;
            }
            const float p = __expf(s - m);
            l += p;
            #pragma unroll
            for (int c = 0; c < CH; ++c) o[c] = fmaf(p, Vs[k][c], o[c]);
        }
    }
    const float linv = 1.f / l;
    const size_t ob = ((size_t)(i*NRES) + tid) * DM + h*CH;
    #pragma unroll
    for (int c = 0; c < CH; ++c) {
        const float gv = __bfloat162float(gows[ob + c]);   // read gate
        gows[ob + c] = tob(o[c] * linv * gv);              // overwrite with o (same addr)
    }
}

// ---------- Kernel 3: output projection, MFMA (B split; A is bf16-exact) ----------
// grid NPOS/256, block 512 (8 waves = 4M x 2N; wave: 64 rows x 64 cols)
__global__ __launch_bounds__(512)
void k_outproj(const bf16* __restrict__ gows, const bf16* __restrict__ B2h,
               const bf16* __restrict__ B2l, float* __restrict__ out)
{
    __shared__ __align__(16) char As[256 * 256];   // 64 KB: bf16 [256][128], swizzled
    const int tid = threadIdx.x;
    const int p0 = blockIdx.x * 256;
    const int lane = tid & 63, wid = tid >> 6;
    const int wm = wid >> 1, wn = wid & 1;

    short8 bh[4][4];
    {
        const uint4* bp = (const uint4*)B2h;
        #pragma unroll
        for (int ks = 0; ks < 4; ++ks)
            #pragma unroll
            for (int nr = 0; nr < 4; ++nr) {
                uint4 t = bp[(((wn*4 + ks)*4) + nr)*64 + lane];
                bh[ks][nr] = *(short8*)&t;
            }
    }

    // stage A (256x128 bf16) swizzled
    {
        const uint4* src = (const uint4*)(gows + (size_t)p0 * DM);
        #pragma unroll
        for (int it = 0; it < 8; ++it) {
            const int t = tid + it*512;           // 8-bf16 chunk id
            uint4 u = src[t];
            const int row = t >> 4, cb = (t & 15) * 16;
            *(uint4*)(As + ((row*256 + cb) ^ ((row & 7) << 4))) = u;
        }
    }
    __syncthreads();

    floatx4 acc[4][4];
    #pragma unroll
    for (int m = 0; m < 4; ++m)
        #pragma unroll
        for (int n = 0; n < 4; ++n)
            acc[m][n] = (floatx4){0.f, 0.f, 0.f, 0.f};

    const uint4* bpl = (const uint4*)B2l;
    #pragma unroll
    for (int ks = 0; ks < 4; ++ks) {
        short8 a[4];
        #pragma unroll
        for (int m = 0; m < 4; ++m) {
            const int row = wm*64 + m*16 + (lane & 15);
            const int kb = ks*64 + ((lane >> 4) << 4);
            a[m] = *(const short8*)(As + ((row*256 + kb) ^ ((row & 7) << 4)));
        }
        #pragma unroll
        for (int nr = 0; nr < 4; ++nr) {
            uint4 tl = bpl[(((wn*4 + ks)*4) + nr)*64 + lane];
            const short8 bl = *(short8*)&tl;
            #pragma unroll
            for (int m = 0; m < 4; ++m)
                acc[m][nr] = __builtin_amdgcn_mfma_f32_16x16x32_bf16(a[m], bh[ks][nr], acc[m][nr], 0, 0, 0);
            #pragma unroll
            for (int m = 0; m < 4; ++m)
                acc[m][nr] = __builtin_amdgcn_mfma_f32_16x16x32_bf16(a[m], bl, acc[m][nr], 0, 0, 0);
        }
    }

    #pragma unroll
    for (int m = 0; m < 4; ++m) {
        #pragma unroll
        for (int n = 0; n < 4; ++n) {
            const int d = wn*64 + n*16 + (lane & 15);
            #pragma unroll
            for (int r = 0; r < 4; ++r) {
                const int prow = p0 + wm*64 + m*16 + ((lane >> 4) << 2) + r;
                out[(size_t)prow*DM + d] = acc[m][n][r];
            }
        }
    }
}

extern "C" void kernel_launch(void* const* d_in, const int* in_sizes, int n_in,
                              void* d_out, int out_size, void* d_ws, size_t ws_size,
                              hipStream_t stream)
{
    const float* z   = (const float*)d_in[0];
    const float* mb  = (const float*)d_in[1];
    const float* eb  = (const float*)d_in[2];
    const float* wq  = (const float*)d_in[3];
    const float* wk  = (const float*)d_in[4];
    const float* wv  = (const float*)d_in[5];
    const float* wg  = (const float*)d_in[6];
    const float* wo  = (const float*)d_in[7];
    const float* lnw = (const float*)d_in[8];
    const float* lnb = (const float*)d_in[9];
    float* out = (float*)d_out;

    const size_t SEG = (size_t)NPOS * DM;
    bf16* qws  = (bf16*)d_ws;
    bf16* kws  = qws + SEG;
    bf16* vws  = kws + SEG;
    bf16* gows = vws + SEG;          // gate written by lnproj, o written in place by attn
    bf16* Bpkh = gows + SEG;         // 65536
    bf16* Bpkl = Bpkh + 65536;       // 65536
    bf16* B2h  = Bpkl + 65536;       // 16384
    bf16* B2l  = B2h + 16384;        // 16384   (total ws ~105.2 MB)

    k_packw<<<256, 256, 0, stream>>>(wq, wk, wv, wg, Bpkh, Bpkl);
    k_packwo<<<64, 256, 0, stream>>>(wo, B2h, B2l);
    k_lnproj<<<NPOS/64, 512, 0, stream>>>(z, lnw, lnb, Bpkh, Bpkl, qws, kws, vws, gows);
    k_attn<<<dim3(NRES, NH), 320, 0, stream>>>(qws, kws, vws, gows, mb, eb);
    k_outproj<<<NPOS/256, 512, 0, stream>>>(gows, B2h, B2l, out);
}

// Round 5
// 202.607 us; speedup vs baseline: 6.8419x; 3.6158x over previous
//
#include <hip/hip_runtime.h>
#include <hip/hip_bf16.h>

#define NRES 320
#define CZ 128
#define NH 4
#define CH 32
#define DM 128
#define NPOS (NRES*NRES)
#define LN_EPS 1e-5f
#define QSCALE 0.17677669529663687f

using bf16 = __hip_bfloat16;
typedef __attribute__((ext_vector_type(8))) short short8;
typedef __attribute__((ext_vector_type(4))) float floatx4;

__device__ __forceinline__ float bflo(uint32_t u){ return __uint_as_float(u << 16); }
__device__ __forceinline__ float bfhi(uint32_t u){ return __uint_as_float(u & 0xffff0000u); }
__device__ __forceinline__ bf16 tob(float f){ return __float2bfloat16(f); }
__device__ __forceinline__ unsigned short f2bu(float f){
    uint32_t u = __float_as_uint(f);
    uint32_t r = (u + 0x7fffu + ((u >> 16) & 1u)) >> 16;   // RNE
    return (unsigned short)r;
}
__device__ __forceinline__ float bu2f(unsigned short b){
    return __uint_as_float((uint32_t)b << 16);
}
__device__ __forceinline__ uint4 pk8(const unsigned short* u){
    uint4 r;
    r.x = (uint32_t)u[0] | ((uint32_t)u[1] << 16);
    r.y = (uint32_t)u[2] | ((uint32_t)u[3] << 16);
    r.z = (uint32_t)u[4] | ((uint32_t)u[5] << 16);
    r.w = (uint32_t)u[6] | ((uint32_t)u[7] << 16);
    return r;
}
__device__ __forceinline__ uint32_t pk2(float a, float b){
    return (uint32_t)f2bu(a) | ((uint32_t)f2bu(b) << 16);
}

// ---------- pack QKVG weights (hi+lo split) into MFMA B-fragment order ----------
__global__ __launch_bounds__(256)
void k_packw(const float* __restrict__ wq, const float* __restrict__ wk,
             const float* __restrict__ wv, const float* __restrict__ wg,
             bf16* __restrict__ Bpkh, bf16* __restrict__ Bpkl)
{
    const int idx = blockIdx.x * 256 + threadIdx.x;          // 0..65535
    const int j = idx & 7, lane = (idx >> 3) & 63;
    const int nr = (idx >> 9) & 3, ks = (idx >> 11) & 3, wn = idx >> 13;
    const int n = wn*64 + nr*16 + (lane & 15);
    const int k = ks*32 + ((lane >> 4) << 3) + j;
    const float* w = (n >> 7) == 0 ? wq : (n >> 7) == 1 ? wk : (n >> 7) == 2 ? wv : wg;
    const float wv_ = w[(n & 127)*CZ + k];
    const bf16 hb = tob(wv_);
    Bpkh[idx] = hb;
    Bpkl[idx] = tob(wv_ - __bfloat162float(hb));
}

__global__ __launch_bounds__(256)
void k_packwo(const float* __restrict__ wo, bf16* __restrict__ B2h,
              bf16* __restrict__ B2l)
{
    const int idx = blockIdx.x * 256 + threadIdx.x;          // 0..16383
    const int j = idx & 7, lane = (idx >> 3) & 63;
    const int nr = (idx >> 9) & 3, ks = (idx >> 11) & 3, wn = idx >> 13;
    const int n = wn*64 + nr*16 + (lane & 15);
    const int k = ks*32 + ((lane >> 4) << 3) + j;
    const float wv_ = wo[n*DM + k];
    const bf16 hb = tob(wv_);
    B2h[idx] = hb;
    B2l[idx] = tob(wv_ - __bfloat162float(hb));
}

// ---------- Kernel 1: LN + QKVG projection, split-bf16 MFMA ----------
__global__ __launch_bounds__(512)
void k_lnproj(const float* __restrict__ z, const float* __restrict__ ln_w,
              const float* __restrict__ ln_b, const bf16* __restrict__ Bpkh,
              const bf16* __restrict__ Bpkl,
              bf16* __restrict__ qws, bf16* __restrict__ kws,
              bf16* __restrict__ vws, bf16* __restrict__ gows)
{
    __shared__ __align__(16) char Ash[64 * 256];
    __shared__ __align__(16) char Asl[64 * 256];
    const int tid = threadIdx.x;
    const int p0 = blockIdx.x * 64;
    const int lane = tid & 63, wid = tid >> 6;

    short8 bh[4][4];
    {
        const uint4* bp = (const uint4*)Bpkh;
        #pragma unroll
        for (int ks = 0; ks < 4; ++ks)
            #pragma unroll
            for (int nr = 0; nr < 4; ++nr) {
                uint4 t = bp[(((wid*4 + ks)*4) + nr)*64 + lane];
                bh[ks][nr] = *(short8*)&t;
            }
    }

    {
        const int r = tid >> 3, c0 = (tid & 7) * 16;
        const float* zp = z + (size_t)(p0 + r)*CZ + c0;
        float v[16];
        {
            float4 t0 = *(const float4*)(zp + 0);
            float4 t1 = *(const float4*)(zp + 4);
            float4 t2 = *(const float4*)(zp + 8);
            float4 t3 = *(const float4*)(zp + 12);
            v[0]=t0.x; v[1]=t0.y; v[2]=t0.z; v[3]=t0.w;
            v[4]=t1.x; v[5]=t1.y; v[6]=t1.z; v[7]=t1.w;
            v[8]=t2.x; v[9]=t2.y; v[10]=t2.z; v[11]=t2.w;
            v[12]=t3.x; v[13]=t3.y; v[14]=t3.z; v[15]=t3.w;
        }
        float s = 0.f, s2 = 0.f;
        #pragma unroll
        for (int c = 0; c < 16; ++c) { s += v[c]; s2 = fmaf(v[c], v[c], s2); }
        s  += __shfl_xor(s, 1);  s  += __shfl_xor(s, 2);  s  += __shfl_xor(s, 4);
        s2 += __shfl_xor(s2, 1); s2 += __shfl_xor(s2, 2); s2 += __shfl_xor(s2, 4);
        const float mu = s * 0.0078125f;
        const float rs = rsqrtf(s2 * 0.0078125f - mu*mu + LN_EPS);
        unsigned short uh[16], ul[16];
        #pragma unroll
        for (int c = 0; c < 16; ++c) {
            const float vn = (v[c] - mu) * rs * ln_w[c0 + c] + ln_b[c0 + c];
            const unsigned short hh = f2bu(vn);
            uh[c] = hh;
            ul[c] = f2bu(vn - bu2f(hh));
        }
        const int base = r*256 + c0*2;
        const int swz = (r & 7) << 4;
        *(uint4*)(Ash + ((base     ) ^ swz)) = pk8(&uh[0]);
        *(uint4*)(Ash + ((base + 16) ^ swz)) = pk8(&uh[8]);
        *(uint4*)(Asl + ((base     ) ^ swz)) = pk8(&ul[0]);
        *(uint4*)(Asl + ((base + 16) ^ swz)) = pk8(&ul[8]);
    }
    __syncthreads();

    floatx4 acc[4][4];
    #pragma unroll
    for (int m = 0; m < 4; ++m)
        #pragma unroll
        for (int n = 0; n < 4; ++n)
            acc[m][n] = (floatx4){0.f, 0.f, 0.f, 0.f};

    const uint4* bpl = (const uint4*)Bpkl;
    #pragma unroll
    for (int ks = 0; ks < 4; ++ks) {
        short8 ah[4], al[4];
        #pragma unroll
        for (int m = 0; m < 4; ++m) {
            const int row = m*16 + (lane & 15);
            const int kb = ks*64 + ((lane >> 4) << 4);
            const int off = (row*256 + kb) ^ ((row & 7) << 4);
            ah[m] = *(const short8*)(Ash + off);
            al[m] = *(const short8*)(Asl + off);
        }
        #pragma unroll
        for (int nr = 0; nr < 4; ++nr) {
            uint4 tl = bpl[(((wid*4 + ks)*4) + nr)*64 + lane];
            const short8 bl = *(short8*)&tl;
            #pragma unroll
            for (int m = 0; m < 4; ++m)
                acc[m][nr] = __builtin_amdgcn_mfma_f32_16x16x32_bf16(ah[m], bh[ks][nr], acc[m][nr], 0, 0, 0);
            #pragma unroll
            for (int m = 0; m < 4; ++m)
                acc[m][nr] = __builtin_amdgcn_mfma_f32_16x16x32_bf16(al[m], bh[ks][nr], acc[m][nr], 0, 0, 0);
            #pragma unroll
            for (int m = 0; m < 4; ++m)
                acc[m][nr] = __builtin_amdgcn_mfma_f32_16x16x32_bf16(ah[m], bl, acc[m][nr], 0, 0, 0);
        }
    }

    const int i = p0 / NRES;
    const int j0 = p0 % NRES;
    #pragma unroll
    for (int n = 0; n < 4; ++n) {
        const int e = wid*64 + n*16 + (lane & 15);
        const int h = (e >> 5) & 3, c = e & 31;
        #pragma unroll
        for (int m = 0; m < 4; ++m) {
            const int rl0 = m*16 + ((lane >> 4) << 2);
            #pragma unroll
            for (int r = 0; r < 4; ++r) {
                const float val = acc[m][n][r];
                const int jj = j0 + rl0 + r;
                const size_t hidx = ((size_t)((i*NH + h)*NRES) + jj)*CH + c;
                if (wid < 2)       qws[hidx] = tob(val * QSCALE);
                else if (wid < 4)  kws[hidx] = tob(val);
                else if (wid < 6)  vws[hidx] = tob(val);
                else gows[(size_t)(p0 + rl0 + r)*DM + (e & 127)] =
                         tob(1.f / (1.f + __expf(-val)));
            }
        }
    }
}

// ---------------- Kernel 2: MFMA flash attention per (i, h) ----------------
// block 320 (5 waves, wave w owns q in [64w, 64w+64)); g->o in place in gows.
// Swapped orientation: S^T = K·Q^T, O^T = V^T·P^T so softmax q is lane-local.
__global__ __launch_bounds__(320, 2)
void k_attn(const bf16* __restrict__ qws, const bf16* __restrict__ kws,
            const bf16* __restrict__ vws, bf16* __restrict__ gows,
            const float* __restrict__ mask_bias, const float* __restrict__ edge_bias)
{
    // Ks[320][40]bf16 @0 (25600) | Vt[32][328]bf16 @25600 (20992)
    // Ps 5x[64][40]bf16 @46592 (25600; Vnat temp [320][32] lives here pre-loop)
    // mbs f32[320] @72192 (1280)  => total 73472 B -> 2 blocks/CU
    __shared__ __align__(16) char smem[73472];
    constexpr int KS_OFF = 0, VT_OFF = 25600, PS_OFF = 46592, MB_OFF = 72192;
    const int i = blockIdx.x, h = blockIdx.y;
    const int tid = threadIdx.x;
    const int lane = tid & 63, w = tid >> 6;
    const int l15 = lane & 15, g = lane >> 4;
    const size_t slab = (size_t)(i*NH + h) * NRES * CH;

    // stage K -> Ks (padded rows), V -> Vnat (linear, in Ps area), mb -> mbs
    {
        const uint4* kg = (const uint4*)(kws + slab);
        const uint4* vg = (const uint4*)(vws + slab);
        #pragma unroll
        for (int it = 0; it < 4; ++it) {
            const int idx = tid + it*320;            // 1280 16B-chunks
            const int row = idx >> 2, gc = idx & 3;
            *(uint4*)(smem + KS_OFF + row*80 + gc*16) = kg[idx];
            *(uint4*)(smem + PS_OFF + row*64 + gc*16) = vg[idx];
        }
        ((float*)(smem + MB_OFF))[tid] = mask_bias[(size_t)i*NRES + tid];
    }
    // Q B-frags straight from global (independent of LDS)
    short8 bq[4];
    {
        const uint4* qg = (const uint4*)(qws + slab);
        #pragma unroll
        for (int nf = 0; nf < 4; ++nf) {
            uint4 t = qg[(64*w + 16*nf + l15)*4 + g];
            bq[nf] = *(short8*)&t;
        }
    }
    __syncthreads();
    // transpose Vnat[k][c] -> Vt[c][k] (row stride 328 bf16 = 656 B)
    {
        const int c = tid & 31, kb = (tid >> 5) * 32;
        #pragma unroll
        for (int s2 = 0; s2 < 16; ++s2) {
            const uint32_t lo = *(const unsigned short*)(smem + PS_OFF + ((kb + 2*s2    )*32 + c)*2);
            const uint32_t hi = *(const unsigned short*)(smem + PS_OFF + ((kb + 2*s2 + 1)*32 + c)*2);
            *(uint32_t*)(smem + VT_OFF + c*656 + kb*2 + s2*4) = lo | (hi << 16);
        }
    }
    __syncthreads();

    const float2* ebp = (const float2*)(edge_bias + (size_t)h*NRES*NRES);
    char* psb = smem + PS_OFF + w*5120;

    floatx4 o[2][4];
    #pragma unroll
    for (int ma = 0; ma < 2; ++ma)
        #pragma unroll
        for (int nf = 0; nf < 4; ++nf)
            o[ma][nf] = (floatx4){0.f, 0.f, 0.f, 0.f};
    float m[4] = {-1e30f, -1e30f, -1e30f, -1e30f};
    float l[4] = {0.f, 0.f, 0.f, 0.f};

    for (int t = 0; t < 10; ++t) {
        // K A-frags (rows k = 32t+16mi+l15, c = 8g..8g+7)
        const short8 ak0 = *(const short8*)(smem + KS_OFF + (32*t +      l15)*80 + g*16);
        const short8 ak1 = *(const short8*)(smem + KS_OFF + (32*t + 16 + l15)*80 + g*16);
        // edge bias: f32 pairs, L2/L3-hot
        float2 ebv[4][2][2];
        #pragma unroll
        for (int nf = 0; nf < 4; ++nf) {
            const int jq = 64*w + 16*nf + l15;
            #pragma unroll
            for (int mi = 0; mi < 2; ++mi)
                #pragma unroll
                for (int rp = 0; rp < 2; ++rp)
                    ebv[nf][mi][rp] = ebp[(size_t)jq*160 + 16*t + 8*mi + 2*g + rp];
        }
        // S^T = K·Q^T
        floatx4 sa[2][4];
        #pragma unroll
        for (int nf = 0; nf < 4; ++nf) {
            sa[0][nf] = __builtin_amdgcn_mfma_f32_16x16x32_bf16(ak0, bq[nf], (floatx4){0.f,0.f,0.f,0.f}, 0, 0, 0);
            sa[1][nf] = __builtin_amdgcn_mfma_f32_16x16x32_bf16(ak1, bq[nf], (floatx4){0.f,0.f,0.f,0.f}, 0, 0, 0);
        }
        // mask bias (broadcast reads)
        float2 mbv[2][2];
        #pragma unroll
        for (int mi = 0; mi < 2; ++mi)
            #pragma unroll
            for (int rp = 0; rp < 2; ++rp)
                mbv[mi][rp] = *(const float2*)(smem + MB_OFF + (32*t + 16*mi + 4*g + 2*rp)*4);
        // biases + per-q tile max
        float sv[4][2][4];
        float pmax[4];
        #pragma unroll
        for (int nf = 0; nf < 4; ++nf) {
            #pragma unroll
            for (int mi = 0; mi < 2; ++mi) {
                sv[nf][mi][0] = sa[mi][nf][0] + (ebv[nf][mi][0].x + mbv[mi][0].x);
                sv[nf][mi][1] = sa[mi][nf][1] + (ebv[nf][mi][0].y + mbv[mi][0].y);
                sv[nf][mi][2] = sa[mi][nf][2] + (ebv[nf][mi][1].x + mbv[mi][1].x);
                sv[nf][mi][3] = sa[mi][nf][3] + (ebv[nf][mi][1].y + mbv[mi][1].y);
            }
            float pm = fmaxf(fmaxf(fmaxf(sv[nf][0][0], sv[nf][0][1]), fmaxf(sv[nf][0][2], sv[nf][0][3])),
                             fmaxf(fmaxf(sv[nf][1][0], sv[nf][1][1]), fmaxf(sv[nf][1][2], sv[nf][1][3])));
            pm = fmaxf(pm, __shfl_xor(pm, 16));
            pm = fmaxf(pm, __shfl_xor(pm, 32));
            pmax[nf] = pm;
        }
        // defer-max rescale (rare)
        float gm = fmaxf(fmaxf(pmax[0] - m[0], pmax[1] - m[1]),
                         fmaxf(pmax[2] - m[2], pmax[3] - m[3]));
        if (__any(gm > 8.0f)) {
            #pragma unroll
            for (int nf = 0; nf < 4; ++nf) {
                const float mn = fmaxf(m[nf], pmax[nf]);
                const float sc = __expf(m[nf] - mn);
                l[nf] *= sc;
                #pragma unroll
                for (int ma = 0; ma < 2; ++ma)
                    #pragma unroll
                    for (int r = 0; r < 4; ++r)
                        o[ma][nf][r] *= sc;
                m[nf] = mn;
            }
        }
        // p = exp(s - m), accumulate partial l, pack to bf16, write P to own LDS
        #pragma unroll
        for (int nf = 0; nf < 4; ++nf) {
            const int qrow = 16*nf + l15;
            #pragma unroll
            for (int mi = 0; mi < 2; ++mi) {
                const float p0 = __expf(sv[nf][mi][0] - m[nf]);
                const float p1 = __expf(sv[nf][mi][1] - m[nf]);
                const float p2 = __expf(sv[nf][mi][2] - m[nf]);
                const float p3 = __expf(sv[nf][mi][3] - m[nf]);
                l[nf] += (p0 + p1) + (p2 + p3);
                *(uint32_t*)(psb + qrow*80 + mi*32 + g*8 + 0) = pk2(p0, p1);
                *(uint32_t*)(psb + qrow*80 + mi*32 + g*8 + 4) = pk2(p2, p3);
            }
        }
        // PV: O^T += V^T · P^T (same-wave LDS round-trip; lgkmcnt only)
        const short8 av0 = *(const short8*)(smem + VT_OFF + (     l15)*656 + t*64 + g*16);
        const short8 av1 = *(const short8*)(smem + VT_OFF + (16 + l15)*656 + t*64 + g*16);
        short8 bp[4];
        #pragma unroll
        for (int nf = 0; nf < 4; ++nf)
            bp[nf] = *(const short8*)(psb + (16*nf + l15)*80 + g*16);
        #pragma unroll
        for (int nf = 0; nf < 4; ++nf) {
            o[0][nf] = __builtin_amdgcn_mfma_f32_16x16x32_bf16(av0, bp[nf], o[0][nf], 0, 0, 0);
            o[1][nf] = __builtin_amdgcn_mfma_f32_16x16x32_bf16(av1, bp[nf], o[1][nf], 0, 0, 0);
        }
    }

    // combine partial l across the 4 k-groups, then gate+store (b32 packed)
    float linv[4];
    #pragma unroll
    for (int nf = 0; nf < 4; ++nf) {
        float ls = l[nf];
        ls += __shfl_xor(ls, 16);
        ls += __shfl_xor(ls, 32);
        linv[nf] = 1.f / ls;
    }
    uint32_t* gp = (uint32_t*)gows;
    #pragma unroll
    for (int nf = 0; nf < 4; ++nf) {
        const int jq = 64*w + 16*nf + l15;
        #pragma unroll
        for (int ma = 0; ma < 2; ++ma)
            #pragma unroll
            for (int rp = 0; rp < 2; ++rp) {
                const size_t idx = ((size_t)(i*NRES + jq))*64 + h*16 + 8*ma + 2*g + rp;
                const uint32_t u = gp[idx];
                const float v0 = o[ma][nf][2*rp    ] * linv[nf] * bflo(u);
                const float v1 = o[ma][nf][2*rp + 1] * linv[nf] * bfhi(u);
                gp[idx] = pk2(v0, v1);
            }
    }
}

// ---------- Kernel 3: output projection, MFMA (B split; A is bf16-exact) ----------
__global__ __launch_bounds__(512)
void k_outproj(const bf16* __restrict__ gows, const bf16* __restrict__ B2h,
               const bf16* __restrict__ B2l, float* __restrict__ out)
{
    __shared__ __align__(16) char As[256 * 256];
    const int tid = threadIdx.x;
    const int p0 = blockIdx.x * 256;
    const int lane = tid & 63, wid = tid >> 6;
    const int wm = wid >> 1, wn = wid & 1;

    short8 bh[4][4];
    {
        const uint4* bp = (const uint4*)B2h;
        #pragma unroll
        for (int ks = 0; ks < 4; ++ks)
            #pragma unroll
            for (int nr = 0; nr < 4; ++nr) {
                uint4 t = bp[(((wn*4 + ks)*4) + nr)*64 + lane];
                bh[ks][nr] = *(short8*)&t;
            }
    }

    {
        const uint4* src = (const uint4*)(gows + (size_t)p0 * DM);
        #pragma unroll
        for (int it = 0; it < 8; ++it) {
            const int t = tid + it*512;
            uint4 u = src[t];
            const int row = t >> 4, cb = (t & 15) * 16;
            *(uint4*)(As + ((row*256 + cb) ^ ((row & 7) << 4))) = u;
        }
    }
    __syncthreads();

    floatx4 acc[4][4];
    #pragma unroll
    for (int m = 0; m < 4; ++m)
        #pragma unroll
        for (int n = 0; n < 4; ++n)
            acc[m][n] = (floatx4){0.f, 0.f, 0.f, 0.f};

    const uint4* bpl = (const uint4*)B2l;
    #pragma unroll
    for (int ks = 0; ks < 4; ++ks) {
        short8 a[4];
        #pragma unroll
        for (int m = 0; m < 4; ++m) {
            const int row = wm*64 + m*16 + (lane & 15);
            const int kb = ks*64 + ((lane >> 4) << 4);
            a[m] = *(const short8*)(As + ((row*256 + kb) ^ ((row & 7) << 4)));
        }
        #pragma unroll
        for (int nr = 0; nr < 4; ++nr) {
            uint4 tl = bpl[(((wn*4 + ks)*4) + nr)*64 + lane];
            const short8 bl = *(short8*)&tl;
            #pragma unroll
            for (int m = 0; m < 4; ++m)
                acc[m][nr] = __builtin_amdgcn_mfma_f32_16x16x32_bf16(a[m], bh[ks][nr], acc[m][nr], 0, 0, 0);
            #pragma unroll
            for (int m = 0; m < 4; ++m)
                acc[m][nr] = __builtin_amdgcn_mfma_f32_16x16x32_bf16(a[m], bl, acc[m][nr], 0, 0, 0);
        }
    }

    #pragma unroll
    for (int m = 0; m < 4; ++m) {
        #pragma unroll
        for (int n = 0; n < 4; ++n) {
            const int d = wn*64 + n*16 + (lane & 15);
            #pragma unroll
            for (int r = 0; r < 4; ++r) {
                const int prow = p0 + wm*64 + m*16 + ((lane >> 4) << 2) + r;
                out[(size_t)prow*DM + d] = acc[m][n][r];
            }
        }
    }
}

extern "C" void kernel_launch(void* const* d_in, const int* in_sizes, int n_in,
                              void* d_out, int out_size, void* d_ws, size_t ws_size,
                              hipStream_t stream)
{
    const float* z   = (const float*)d_in[0];
    const float* mb  = (const float*)d_in[1];
    const float* eb  = (const float*)d_in[2];
    const float* wq  = (const float*)d_in[3];
    const float* wk  = (const float*)d_in[4];
    const float* wv  = (const float*)d_in[5];
    const float* wg  = (const float*)d_in[6];
    const float* wo  = (const float*)d_in[7];
    const float* lnw = (const float*)d_in[8];
    const float* lnb = (const float*)d_in[9];
    float* out = (float*)d_out;

    const size_t SEG = (size_t)NPOS * DM;
    bf16* qws  = (bf16*)d_ws;
    bf16* kws  = qws + SEG;
    bf16* vws  = kws + SEG;
    bf16* gows = vws + SEG;
    bf16* Bpkh = gows + SEG;
    bf16* Bpkl = Bpkh + 65536;
    bf16* B2h  = Bpkl + 65536;
    bf16* B2l  = B2h + 16384;

    k_packw<<<256, 256, 0, stream>>>(wq, wk, wv, wg, Bpkh, Bpkl);
    k_packwo<<<64, 256, 0, stream>>>(wo, B2h, B2l);
    k_lnproj<<<NPOS/64, 512, 0, stream>>>(z, lnw, lnb, Bpkh, Bpkl, qws, kws, vws, gows);
    k_attn<<<dim3(NRES, NH), 320, 0, stream>>>(qws, kws, vws, gows, mb, eb);
    k_outproj<<<NPOS/256, 512, 0, stream>>>(gows, B2h, B2l, out);
}

// Round 6
// 191.497 us; speedup vs baseline: 7.2388x; 1.0580x over previous
//
#include <hip/hip_runtime.h>
#include <hip/hip_bf16.h>

#define NRES 320
#define CZ 128
#define NH 4
#define CH 32
#define DM 128
#define NPOS (NRES*NRES)
#define LN_EPS 1e-5f
#define QSCALE 0.17677669529663687f

using bf16 = __hip_bfloat16;
typedef __attribute__((ext_vector_type(8))) short short8;
typedef __attribute__((ext_vector_type(4))) float floatx4;

__device__ __forceinline__ float bflo(uint32_t u){ return __uint_as_float(u << 16); }
__device__ __forceinline__ float bfhi(uint32_t u){ return __uint_as_float(u & 0xffff0000u); }
__device__ __forceinline__ bf16 tob(float f){ return __float2bfloat16(f); }
__device__ __forceinline__ unsigned short f2bu(float f){
    uint32_t u = __float_as_uint(f);
    uint32_t r = (u + 0x7fffu + ((u >> 16) & 1u)) >> 16;   // RNE
    return (unsigned short)r;
}
__device__ __forceinline__ float bu2f(unsigned short b){
    return __uint_as_float((uint32_t)b << 16);
}
__device__ __forceinline__ uint4 pk8(const unsigned short* u){
    uint4 r;
    r.x = (uint32_t)u[0] | ((uint32_t)u[1] << 16);
    r.y = (uint32_t)u[2] | ((uint32_t)u[3] << 16);
    r.z = (uint32_t)u[4] | ((uint32_t)u[5] << 16);
    r.w = (uint32_t)u[6] | ((uint32_t)u[7] << 16);
    return r;
}
__device__ __forceinline__ uint32_t pk2(float a, float b){
    return (uint32_t)f2bu(a) | ((uint32_t)f2bu(b) << 16);
}

// ---------- pack QKVG weights (hi+lo split) into MFMA B-fragment order ----------
__global__ __launch_bounds__(256)
void k_packw(const float* __restrict__ wq, const float* __restrict__ wk,
             const float* __restrict__ wv, const float* __restrict__ wg,
             bf16* __restrict__ Bpkh, bf16* __restrict__ Bpkl)
{
    const int idx = blockIdx.x * 256 + threadIdx.x;          // 0..65535
    const int j = idx & 7, lane = (idx >> 3) & 63;
    const int nr = (idx >> 9) & 3, ks = (idx >> 11) & 3, wn = idx >> 13;
    const int n = wn*64 + nr*16 + (lane & 15);
    const int k = ks*32 + ((lane >> 4) << 3) + j;
    const float* w = (n >> 7) == 0 ? wq : (n >> 7) == 1 ? wk : (n >> 7) == 2 ? wv : wg;
    const float wv_ = w[(n & 127)*CZ + k];
    const bf16 hb = tob(wv_);
    Bpkh[idx] = hb;
    Bpkl[idx] = tob(wv_ - __bfloat162float(hb));
}

__global__ __launch_bounds__(256)
void k_packwo(const float* __restrict__ wo, bf16* __restrict__ B2h,
              bf16* __restrict__ B2l)
{
    const int idx = blockIdx.x * 256 + threadIdx.x;          // 0..16383
    const int j = idx & 7, lane = (idx >> 3) & 63;
    const int nr = (idx >> 9) & 3, ks = (idx >> 11) & 3, wn = idx >> 13;
    const int n = wn*64 + nr*16 + (lane & 15);
    const int k = ks*32 + ((lane >> 4) << 3) + j;
    const float wv_ = wo[n*DM + k];
    const bf16 hb = tob(wv_);
    B2h[idx] = hb;
    B2l[idx] = tob(wv_ - __bfloat162float(hb));
}

// ---------- pack edge_bias into per-lane fragment order, bf16 ----------
// ebpk[h][t(10)][w(5)][nf(4)][lane(64)][e(8)]; e = mi*4+r
// value = eb[h][q = 64w+16nf+(lane&15)][k = 32t+16mi+4*(lane>>4)+r]
__global__ __launch_bounds__(256)
void k_packeb(const float* __restrict__ eb, bf16* __restrict__ ebpk)
{
    const int idx = blockIdx.x * 256 + threadIdx.x;          // 0..409599
    const int e = idx & 7;
    const int lane = (idx >> 3) & 63;
    const int nf = (idx >> 9) & 3;
    const int w = (idx >> 11) % 5;
    const int t = (idx / 10240) % 10;
    const int h = idx / 102400;
    const int q = w*64 + nf*16 + (lane & 15);
    const int k = t*32 + (e >> 2)*16 + (lane >> 4)*4 + (e & 3);
    ebpk[idx] = tob(eb[((size_t)h*NRES + q)*NRES + k]);
}

// ---------- Kernel 1: LN + QKVG projection, split-bf16 MFMA ----------
__global__ __launch_bounds__(512)
void k_lnproj(const float* __restrict__ z, const float* __restrict__ ln_w,
              const float* __restrict__ ln_b, const bf16* __restrict__ Bpkh,
              const bf16* __restrict__ Bpkl,
              bf16* __restrict__ qws, bf16* __restrict__ kws,
              bf16* __restrict__ vws, bf16* __restrict__ gows)
{
    __shared__ __align__(16) char Ash[64 * 256];
    __shared__ __align__(16) char Asl[64 * 256];
    const int tid = threadIdx.x;
    const int p0 = blockIdx.x * 64;
    const int lane = tid & 63, wid = tid >> 6;

    short8 bh[4][4];
    {
        const uint4* bp = (const uint4*)Bpkh;
        #pragma unroll
        for (int ks = 0; ks < 4; ++ks)
            #pragma unroll
            for (int nr = 0; nr < 4; ++nr) {
                uint4 t = bp[(((wid*4 + ks)*4) + nr)*64 + lane];
                bh[ks][nr] = *(short8*)&t;
            }
    }

    {
        const int r = tid >> 3, c0 = (tid & 7) * 16;
        const float* zp = z + (size_t)(p0 + r)*CZ + c0;
        float v[16];
        {
            float4 t0 = *(const float4*)(zp + 0);
            float4 t1 = *(const float4*)(zp + 4);
            float4 t2 = *(const float4*)(zp + 8);
            float4 t3 = *(const float4*)(zp + 12);
            v[0]=t0.x; v[1]=t0.y; v[2]=t0.z; v[3]=t0.w;
            v[4]=t1.x; v[5]=t1.y; v[6]=t1.z; v[7]=t1.w;
            v[8]=t2.x; v[9]=t2.y; v[10]=t2.z; v[11]=t2.w;
            v[12]=t3.x; v[13]=t3.y; v[14]=t3.z; v[15]=t3.w;
        }
        float s = 0.f, s2 = 0.f;
        #pragma unroll
        for (int c = 0; c < 16; ++c) { s += v[c]; s2 = fmaf(v[c], v[c], s2); }
        s  += __shfl_xor(s, 1);  s  += __shfl_xor(s, 2);  s  += __shfl_xor(s, 4);
        s2 += __shfl_xor(s2, 1); s2 += __shfl_xor(s2, 2); s2 += __shfl_xor(s2, 4);
        const float mu = s * 0.0078125f;
        const float rs = rsqrtf(s2 * 0.0078125f - mu*mu + LN_EPS);
        unsigned short uh[16], ul[16];
        #pragma unroll
        for (int c = 0; c < 16; ++c) {
            const float vn = (v[c] - mu) * rs * ln_w[c0 + c] + ln_b[c0 + c];
            const unsigned short hh = f2bu(vn);
            uh[c] = hh;
            ul[c] = f2bu(vn - bu2f(hh));
        }
        const int base = r*256 + c0*2;
        const int swz = (r & 7) << 4;
        *(uint4*)(Ash + ((base     ) ^ swz)) = pk8(&uh[0]);
        *(uint4*)(Ash + ((base + 16) ^ swz)) = pk8(&uh[8]);
        *(uint4*)(Asl + ((base     ) ^ swz)) = pk8(&ul[0]);
        *(uint4*)(Asl + ((base + 16) ^ swz)) = pk8(&ul[8]);
    }
    __syncthreads();

    floatx4 acc[4][4];
    #pragma unroll
    for (int m = 0; m < 4; ++m)
        #pragma unroll
        for (int n = 0; n < 4; ++n)
            acc[m][n] = (floatx4){0.f, 0.f, 0.f, 0.f};

    const uint4* bpl = (const uint4*)Bpkl;
    #pragma unroll
    for (int ks = 0; ks < 4; ++ks) {
        short8 ah[4], al[4];
        #pragma unroll
        for (int m = 0; m < 4; ++m) {
            const int row = m*16 + (lane & 15);
            const int kb = ks*64 + ((lane >> 4) << 4);
            const int off = (row*256 + kb) ^ ((row & 7) << 4);
            ah[m] = *(const short8*)(Ash + off);
            al[m] = *(const short8*)(Asl + off);
        }
        #pragma unroll
        for (int nr = 0; nr < 4; ++nr) {
            uint4 tl = bpl[(((wid*4 + ks)*4) + nr)*64 + lane];
            const short8 bl = *(short8*)&tl;
            #pragma unroll
            for (int m = 0; m < 4; ++m)
                acc[m][nr] = __builtin_amdgcn_mfma_f32_16x16x32_bf16(ah[m], bh[ks][nr], acc[m][nr], 0, 0, 0);
            #pragma unroll
            for (int m = 0; m < 4; ++m)
                acc[m][nr] = __builtin_amdgcn_mfma_f32_16x16x32_bf16(al[m], bh[ks][nr], acc[m][nr], 0, 0, 0);
            #pragma unroll
            for (int m = 0; m < 4; ++m)
                acc[m][nr] = __builtin_amdgcn_mfma_f32_16x16x32_bf16(ah[m], bl, acc[m][nr], 0, 0, 0);
        }
    }

    const int i = p0 / NRES;
    const int j0 = p0 % NRES;
    #pragma unroll
    for (int n = 0; n < 4; ++n) {
        const int e = wid*64 + n*16 + (lane & 15);
        const int h = (e >> 5) & 3, c = e & 31;
        #pragma unroll
        for (int m = 0; m < 4; ++m) {
            const int rl0 = m*16 + ((lane >> 4) << 2);
            #pragma unroll
            for (int r = 0; r < 4; ++r) {
                const float val = acc[m][n][r];
                const int jj = j0 + rl0 + r;
                const size_t hidx = ((size_t)((i*NH + h)*NRES) + jj)*CH + c;
                if (wid < 2)       qws[hidx] = tob(val * QSCALE);
                else if (wid < 4)  kws[hidx] = tob(val);
                else if (wid < 6)  vws[hidx] = tob(val);
                else gows[(size_t)(p0 + rl0 + r)*DM + (e & 127)] =
                         tob(1.f / (1.f + __expf(-val)));
            }
        }
    }
}

// ---------------- Kernel 2: MFMA flash attention per (i, h) ----------------
// 5 waves x 64 q. S^T = K·Q^T (softmax q lane-local), O^T = V^T·P^T.
// P moved C-layout -> B-frag layout via in-register shuffles (no LDS round-trip).
__global__ __launch_bounds__(320, 2)
void k_attn(const bf16* __restrict__ qws, const bf16* __restrict__ kws,
            const bf16* __restrict__ vws, bf16* __restrict__ gows,
            const float* __restrict__ mask_bias, const bf16* __restrict__ ebpk)
{
    // K frag-linear: 20 frags x 1024B @0 | Vt 32 rows x 688B @20480 | mb f32[320] @42496
    __shared__ __align__(16) char smem[43776];
    constexpr int KS_OFF = 0, VT_OFF = 20480, MB_OFF = 42496;
    const int i = blockIdx.x, h = blockIdx.y;
    const int tid = threadIdx.x;
    const int lane = tid & 63, w = tid >> 6;
    const int l15 = lane & 15, g = lane >> 4;
    const size_t slab = (size_t)(i*NH + h) * NRES * CH;

    // K -> fragment-linear LDS (write & read both canonical lane*16B)
    {
        const uint4* kg = (const uint4*)(kws + slab);
        #pragma unroll
        for (int it = 0; it < 4; ++it) {
            const int idx = tid + it*320;
            const int row = idx >> 2, gc = idx & 3;
            *(uint4*)(smem + KS_OFF + (row >> 4)*1024 + (gc*16 + (row & 15))*16) = kg[idx];
        }
    }
    // V row tid -> Vt columns (rows padded to 688B: 12-dword skew, 2-way max)
    {
        const uint4* vg = (const uint4*)(vws + slab) + tid*4;
        uint32_t dw[16];
        *(uint4*)&dw[0]  = vg[0];
        *(uint4*)&dw[4]  = vg[1];
        *(uint4*)&dw[8]  = vg[2];
        *(uint4*)&dw[12] = vg[3];
        #pragma unroll
        for (int c = 0; c < 32; ++c) {
            const uint32_t d = dw[c >> 1];
            const unsigned short hv = (c & 1) ? (unsigned short)(d >> 16)
                                              : (unsigned short)(d & 0xffffu);
            *(unsigned short*)(smem + VT_OFF + c*688 + tid*2) = hv;
        }
    }
    ((float*)(smem + MB_OFF))[tid] = mask_bias[(size_t)i*NRES + tid];

    // Q B-frags direct from global (coalesced 1KB/instr)
    short8 bq[4];
    {
        const uint4* qg = (const uint4*)(qws + slab);
        #pragma unroll
        for (int nf = 0; nf < 4; ++nf) {
            uint4 t = qg[(64*w + 16*nf + l15)*4 + g];
            bq[nf] = *(short8*)&t;
        }
    }
    __syncthreads();

    const uint4* ebp = (const uint4*)ebpk;
    const int ebbase = h*12800 + w*256 + lane;

    uint4 ebc[4];
    #pragma unroll
    for (int nf = 0; nf < 4; ++nf) ebc[nf] = ebp[ebbase + nf*64];

    floatx4 o[2][4];
    #pragma unroll
    for (int ma = 0; ma < 2; ++ma)
        #pragma unroll
        for (int nf = 0; nf < 4; ++nf)
            o[ma][nf] = (floatx4){0.f, 0.f, 0.f, 0.f};
    float m[4] = {-1e30f, -1e30f, -1e30f, -1e30f};
    float l[4] = {0.f, 0.f, 0.f, 0.f};

    const int srcA = ((lane >> 4) & 1)*32 + l15;
    const int srcB = srcA + 16;
    const bool hisel = (lane & 32) != 0;

    for (int t = 0; t < 10; ++t) {
        // LDS frag reads (canonical / skewed)
        const short8 ak0 = *(const short8*)(smem + KS_OFF + t*2048 + lane*16);
        const short8 ak1 = *(const short8*)(smem + KS_OFF + t*2048 + 1024 + lane*16);
        const short8 av0 = *(const short8*)(smem + VT_OFF + l15*688 + t*64 + g*16);
        const short8 av1 = *(const short8*)(smem + VT_OFF + (16 + l15)*688 + t*64 + g*16);
        // prefetch next tile's bias (coalesced dwordx4; wait lands at copy below)
        const int tn = (t < 9) ? t + 1 : 9;
        uint4 ebn[4];
        #pragma unroll
        for (int nf = 0; nf < 4; ++nf) ebn[nf] = ebp[ebbase + tn*1280 + nf*64];

        // S^T = K·Q^T
        floatx4 sa[2][4];
        #pragma unroll
        for (int nf = 0; nf < 4; ++nf) {
            sa[0][nf] = __builtin_amdgcn_mfma_f32_16x16x32_bf16(ak0, bq[nf], (floatx4){0.f,0.f,0.f,0.f}, 0, 0, 0);
            sa[1][nf] = __builtin_amdgcn_mfma_f32_16x16x32_bf16(ak1, bq[nf], (floatx4){0.f,0.f,0.f,0.f}, 0, 0, 0);
        }
        // mask bias (quad-broadcast LDS reads, uniform over nf)
        float2 mbv[2][2];
        #pragma unroll
        for (int mi = 0; mi < 2; ++mi)
            #pragma unroll
            for (int rp = 0; rp < 2; ++rp)
                mbv[mi][rp] = *(const float2*)(smem + MB_OFF + (32*t + 16*mi + 4*g + 2*rp)*4);

        // s = S^T + eb + mb; lane-local max per nf
        float sv[4][2][4];
        float lmax[4];
        #pragma unroll
        for (int nf = 0; nf < 4; ++nf) {
            const uint4 E = ebc[nf];
            sv[nf][0][0] = sa[0][nf][0] + (bflo(E.x) + mbv[0][0].x);
            sv[nf][0][1] = sa[0][nf][1] + (bfhi(E.x) + mbv[0][0].y);
            sv[nf][0][2] = sa[0][nf][2] + (bflo(E.y) + mbv[0][1].x);
            sv[nf][0][3] = sa[0][nf][3] + (bfhi(E.y) + mbv[0][1].y);
            sv[nf][1][0] = sa[1][nf][0] + (bflo(E.z) + mbv[1][0].x);
            sv[nf][1][1] = sa[1][nf][1] + (bfhi(E.z) + mbv[1][0].y);
            sv[nf][1][2] = sa[1][nf][2] + (bflo(E.w) + mbv[1][1].x);
            sv[nf][1][3] = sa[1][nf][3] + (bfhi(E.w) + mbv[1][1].y);
            lmax[nf] = fmaxf(fmaxf(fmaxf(sv[nf][0][0], sv[nf][0][1]), fmaxf(sv[nf][0][2], sv[nf][0][3])),
                             fmaxf(fmaxf(sv[nf][1][0], sv[nf][1][1]), fmaxf(sv[nf][1][2], sv[nf][1][3])));
        }
        // defer-max: cheap lane-local check; full reduce+rescale only when needed
        const float gm = fmaxf(fmaxf(lmax[0] - m[0], lmax[1] - m[1]),
                               fmaxf(lmax[2] - m[2], lmax[3] - m[3]));
        if (__any(gm > 8.0f)) {
            #pragma unroll
            for (int nf = 0; nf < 4; ++nf) {
                float pm = lmax[nf];
                pm = fmaxf(pm, __shfl_xor(pm, 16));
                pm = fmaxf(pm, __shfl_xor(pm, 32));
                const float mn = fmaxf(m[nf], pm);
                const float sc = __expf(m[nf] - mn);
                l[nf] *= sc;
                #pragma unroll
                for (int ma = 0; ma < 2; ++ma)
                    #pragma unroll
                    for (int r = 0; r < 4; ++r)
                        o[ma][nf][r] *= sc;
                m[nf] = mn;
            }
        }
        // exp, partial-l, pack, and C-layout -> B-frag shuffle (no LDS)
        short8 bp[4];
        #pragma unroll
        for (int nf = 0; nf < 4; ++nf) {
            float p00 = __expf(sv[nf][0][0] - m[nf]);
            float p01 = __expf(sv[nf][0][1] - m[nf]);
            float p02 = __expf(sv[nf][0][2] - m[nf]);
            float p03 = __expf(sv[nf][0][3] - m[nf]);
            float p10 = __expf(sv[nf][1][0] - m[nf]);
            float p11 = __expf(sv[nf][1][1] - m[nf]);
            float p12 = __expf(sv[nf][1][2] - m[nf]);
            float p13 = __expf(sv[nf][1][3] - m[nf]);
            l[nf] += ((p00 + p01) + (p02 + p03)) + ((p10 + p11) + (p12 + p13));
            const uint32_t d00 = pk2(p00, p01), d01 = pk2(p02, p03);
            const uint32_t d10 = pk2(p10, p11), d11 = pk2(p12, p13);
            const uint32_t a0 = (uint32_t)__shfl((int)d00, srcA);
            const uint32_t a1 = (uint32_t)__shfl((int)d01, srcA);
            const uint32_t a2 = (uint32_t)__shfl((int)d10, srcA);
            const uint32_t a3 = (uint32_t)__shfl((int)d11, srcA);
            const uint32_t b0 = (uint32_t)__shfl((int)d00, srcB);
            const uint32_t b1 = (uint32_t)__shfl((int)d01, srcB);
            const uint32_t b2 = (uint32_t)__shfl((int)d10, srcB);
            const uint32_t b3 = (uint32_t)__shfl((int)d11, srcB);
            uint4 u;
            u.x = hisel ? a2 : a0;
            u.y = hisel ? a3 : a1;
            u.z = hisel ? b2 : b0;
            u.w = hisel ? b3 : b1;
            bp[nf] = *(short8*)&u;
        }
        // O^T += V^T · P^T
        #pragma unroll
        for (int nf = 0; nf < 4; ++nf) {
            o[0][nf] = __builtin_amdgcn_mfma_f32_16x16x32_bf16(av0, bp[nf], o[0][nf], 0, 0, 0);
            o[1][nf] = __builtin_amdgcn_mfma_f32_16x16x32_bf16(av1, bp[nf], o[1][nf], 0, 0, 0);
        }
        #pragma unroll
        for (int nf = 0; nf < 4; ++nf) ebc[nf] = ebn[nf];
    }

    // combine partial l across k-groups, then gate+store (b32 packed RMW)
    float linv[4];
    #pragma unroll
    for (int nf = 0; nf < 4; ++nf) {
        float ls = l[nf];
        ls += __shfl_xor(ls, 16);
        ls += __shfl_xor(ls, 32);
        linv[nf] = 1.f / ls;
    }
    uint32_t* gp = (uint32_t*)gows;
    #pragma unroll
    for (int nf = 0; nf < 4; ++nf) {
        const int jq = 64*w + 16*nf + l15;
        #pragma unroll
        for (int ma = 0; ma < 2; ++ma)
            #pragma unroll
            for (int rp = 0; rp < 2; ++rp) {
                const size_t idx = ((size_t)(i*NRES + jq))*64 + h*16 + 8*ma + 2*g + rp;
                const uint32_t u = gp[idx];
                const float v0 = o[ma][nf][2*rp    ] * linv[nf] * bflo(u);
                const float v1 = o[ma][nf][2*rp + 1] * linv[nf] * bfhi(u);
                gp[idx] = pk2(v0, v1);
            }
    }
}

// ---------- Kernel 3: output projection, MFMA (B split; A is bf16-exact) ----------
__global__ __launch_bounds__(512)
void k_outproj(const bf16* __restrict__ gows, const bf16* __restrict__ B2h,
               const bf16* __restrict__ B2l, float* __restrict__ out)
{
    __shared__ __align__(16) char As[256 * 256];
    const int tid = threadIdx.x;
    const int p0 = blockIdx.x * 256;
    const int lane = tid & 63, wid = tid >> 6;
    const int wm = wid >> 1, wn = wid & 1;

    short8 bh[4][4];
    {
        const uint4* bp = (const uint4*)B2h;
        #pragma unroll
        for (int ks = 0; ks < 4; ++ks)
            #pragma unroll
            for (int nr = 0; nr < 4; ++nr) {
                uint4 t = bp[(((wn*4 + ks)*4) + nr)*64 + lane];
                bh[ks][nr] = *(short8*)&t;
            }
    }

    {
        const uint4* src = (const uint4*)(gows + (size_t)p0 * DM);
        #pragma unroll
        for (int it = 0; it < 8; ++it) {
            const int t = tid + it*512;
            uint4 u = src[t];
            const int row = t >> 4, cb = (t & 15) * 16;
            *(uint4*)(As + ((row*256 + cb) ^ ((row & 7) << 4))) = u;
        }
    }
    __syncthreads();

    floatx4 acc[4][4];
    #pragma unroll
    for (int m = 0; m < 4; ++m)
        #pragma unroll
        for (int n = 0; n < 4; ++n)
            acc[m][n] = (floatx4){0.f, 0.f, 0.f, 0.f};

    const uint4* bpl = (const uint4*)B2l;
    #pragma unroll
    for (int ks = 0; ks < 4; ++ks) {
        short8 a[4];
        #pragma unroll
        for (int m = 0; m < 4; ++m) {
            const int row = wm*64 + m*16 + (lane & 15);
            const int kb = ks*64 + ((lane >> 4) << 4);
            a[m] = *(const short8*)(As + ((row*256 + kb) ^ ((row & 7) << 4)));
        }
        #pragma unroll
        for (int nr = 0; nr < 4; ++nr) {
            uint4 tl = bpl[(((wn*4 + ks)*4) + nr)*64 + lane];
            const short8 bl = *(short8*)&tl;
            #pragma unroll
            for (int m = 0; m < 4; ++m)
                acc[m][nr] = __builtin_amdgcn_mfma_f32_16x16x32_bf16(a[m], bh[ks][nr], acc[m][nr], 0, 0, 0);
            #pragma unroll
            for (int m = 0; m < 4; ++m)
                acc[m][nr] = __builtin_amdgcn_mfma_f32_16x16x32_bf16(a[m], bl, acc[m][nr], 0, 0, 0);
        }
    }

    #pragma unroll
    for (int m = 0; m < 4; ++m) {
        #pragma unroll
        for (int n = 0; n < 4; ++n) {
            const int d = wn*64 + n*16 + (lane & 15);
            #pragma unroll
            for (int r = 0; r < 4; ++r) {
                const int prow = p0 + wm*64 + m*16 + ((lane >> 4) << 2) + r;
                out[(size_t)prow*DM + d] = acc[m][n][r];
            }
        }
    }
}

extern "C" void kernel_launch(void* const* d_in, const int* in_sizes, int n_in,
                              void* d_out, int out_size, void* d_ws, size_t ws_size,
                              hipStream_t stream)
{
    const float* z   = (const float*)d_in[0];
    const float* mb  = (const float*)d_in[1];
    const float* eb  = (const float*)d_in[2];
    const float* wq  = (const float*)d_in[3];
    const float* wk  = (const float*)d_in[4];
    const float* wv  = (const float*)d_in[5];
    const float* wg  = (const float*)d_in[6];
    const float* wo  = (const float*)d_in[7];
    const float* lnw = (const float*)d_in[8];
    const float* lnb = (const float*)d_in[9];
    float* out = (float*)d_out;

    const size_t SEG = (size_t)NPOS * DM;
    bf16* qws  = (bf16*)d_ws;
    bf16* kws  = qws + SEG;
    bf16* vws  = kws + SEG;
    bf16* gows = vws + SEG;
    bf16* Bpkh = gows + SEG;
    bf16* Bpkl = Bpkh + 65536;
    bf16* B2h  = Bpkl + 65536;
    bf16* B2l  = B2h + 16384;
    bf16* ebpk = B2l + 16384;        // 409,600 bf16

    k_packw<<<256, 256, 0, stream>>>(wq, wk, wv, wg, Bpkh, Bpkl);
    k_packwo<<<64, 256, 0, stream>>>(wo, B2h, B2l);
    k_packeb<<<1600, 256, 0, stream>>>(eb, ebpk);
    k_lnproj<<<NPOS/64, 512, 0, stream>>>(z, lnw, lnb, Bpkh, Bpkl, qws, kws, vws, gows);
    k_attn<<<dim3(NRES, NH), 320, 0, stream>>>(qws, kws, vws, gows, mb, ebpk);
    k_outproj<<<NPOS/256, 512, 0, stream>>>(gows, B2h, B2l, out);
}